// Round 11
// baseline (609.982 us; speedup 1.0000x reference)
//
#include <hip/hip_runtime.h>
#include <hip/hip_fp16.h>

#define OUT_FEAT 11008
#define IN_FEAT  4096
#define HAD      128

typedef __attribute__((ext_vector_type(8))) _Float16 f16x8;
typedef __attribute__((ext_vector_type(4))) float    f32x4;

// ---------------------------------------------------------------- stage 16B/lane
__device__ __forceinline__ void lds_load16(const _Float16* g, _Float16* l) {
    __builtin_amdgcn_global_load_lds(
        (const __attribute__((address_space(1))) void*)g,
        (__attribute__((address_space(3))) void*)l, 16, 0, 0);
}

// ---------------------------------------------------------------- kernel 1: merged prep, role-interleaved
// Bresenham split over 6848 blocks: 4096 transpose + 2752 rotate, interleaved ~3:2 so
// memory-bound (transpose) and VALU-bound (rotate) blocks co-schedule on every CU.
// T(b) = b*64/107 (= b*4096/6848); transpose iff T(b+1)>T(b), t_idx = T(b); else r_idx = b - T(b).
__global__ __launch_bounds__(256, 2) void k_prep(const float* __restrict__ Rl,
                                                 const float* __restrict__ Rr,
                                                 const float* __restrict__ inp,
                                                 _Float16* __restrict__ Bt,
                                                 __half* __restrict__ W,
                                                 unsigned* __restrict__ amax) {
    __shared__ char smem[65536];
    int bid = blockIdx.x;
    int t   = threadIdx.x;

    if (bid == 0 && t == 0) *amax = 0u;  // any prep block precedes gemm's atomics (stream order)

    unsigned tb  = ((unsigned)bid * 64u) / 107u;
    unsigned tb1 = ((unsigned)(bid + 1) * 64u) / 107u;

    if (tb1 > tb) {
        // ---------------- transpose+convert (t_idx = tb in [0,4096)) ----------------
        float (*tile)[65] = (float(*)[65])smem;
        int n0 = (int)(tb & 63u) * 64;
        int k0 = (int)(tb >> 6) * 64;
        int tn = t & 63;
        int tr = t >> 6;
#pragma unroll
        for (int r = 0; r < 16; ++r) {
            int kk = r * 4 + tr;
            tile[kk][tn] = Rl[(size_t)(k0 + kk) * IN_FEAT + n0 + tn];
        }
        __syncthreads();
#pragma unroll
        for (int r = 0; r < 16; ++r) {
            int nn = r * 4 + tr;
            Bt[(size_t)(n0 + nn) * IN_FEAT + k0 + tn] = (_Float16)tile[tn][nn];
        }
        return;
    }

    // ---------------- rotate (r_idx = bid - tb in [0,2752)) ----------------
    __half2* sR2 = (__half2*)smem;            // [k][64 j-pairs]  32 KB
    __half2* sX2 = (__half2*)(smem + 32768);  // [k][64 i-pairs]  32 KB
    int rb = bid - (int)tb;
    int i0 = (rb & 31) * 128;
    int b  = rb >> 5;

#pragma unroll
    for (int r = 0; r < 32; ++r) {
        int idx = r * 256 + t;  // half2 index
        float2 v = *(const float2*)&Rr[(size_t)idx * 2];
        sR2[idx] = __floats2half2_rn(v.x, v.y);
    }
    const float* xsrc = inp + (size_t)b * HAD * IN_FEAT + i0;
#pragma unroll
    for (int r = 0; r < 32; ++r) {
        int idx = r * 256 + t;
        int k = idx >> 6, ip = idx & 63;
        float2 v = *(const float2*)&xsrc[(size_t)k * IN_FEAT + ip * 2];
        sX2[idx] = __floats2half2_rn(v.x, v.y);
    }
    __syncthreads();

    int tx = t & 15, ty = t >> 4;
    __half2 acc2[8][4];
#pragma unroll
    for (int j = 0; j < 8; ++j)
#pragma unroll
        for (int c = 0; c < 4; ++c) acc2[j][c] = __float2half2_rn(0.f);

    for (int k = 0; k < 128; ++k) {
        const __half2* rp = &sR2[k * 64 + ty * 4];
        __half2 rr[4] = {rp[0], rp[1], rp[2], rp[3]};
        const __half2* xp = &sX2[k * 64 + tx * 4];
        __half2 xv[4] = {xp[0], xp[1], xp[2], xp[3]};
#pragma unroll
        for (int q = 0; q < 4; ++q) {
            __half2 rlo = __low2half2(rr[q]);
            __half2 rhi = __high2half2(rr[q]);
#pragma unroll
            for (int c = 0; c < 4; ++c) {
                acc2[2 * q][c]     = __hfma2(rlo, xv[c], acc2[2 * q][c]);
                acc2[2 * q + 1][c] = __hfma2(rhi, xv[c], acc2[2 * q + 1][c]);
            }
        }
    }

#pragma unroll
    for (int jj = 0; jj < 8; ++jj) {
        size_t row = (size_t)(b * HAD + ty * 8 + jj) * IN_FEAT;
        union { __half2 h2[4]; f16x8 v; } u;
#pragma unroll
        for (int c = 0; c < 4; ++c) u.h2[c] = acc2[jj][c];
        *(f16x8*)&W[row + i0 + tx * 8] = u.v;
    }
}

// ---------------------------------------------------------------- kernel 3: 256x256 BK=64, branch-free unrolled pipeline
// Measured-best structure (R8/R10: ~440-449 us, MfmaUtil 36.5%, 0 bank conflicts). FROZEN.
#define BM 256
#define BN 256
#define BK 64
#define NT 64  // IN_FEAT / BK

#define DSA(dst, MH, KS, BUF)                                                 \
  _Pragma("unroll") for (int i_ = 0; i_ < 4; ++i_)                            \
      dst[i_] = *(const f16x8*)(aBase + (BUF)*16384 + ((MH)*4 + i_)*1024 +    \
                                ((KS) ? pk1 : pk0));

#define DSB(dst, KS, BUF)                                                     \
  _Pragma("unroll") for (int i_ = 0; i_ < 4; ++i_)                            \
      dst[i_] = *(const f16x8*)(bBase + (BUF)*16384 + i_*1024 +               \
                                ((KS) ? pk1 : pk0));

#define MFMAQ(AB, ar, br)                                                     \
  _Pragma("unroll") for (int mi_ = 0; mi_ < 4; ++mi_)                         \
  _Pragma("unroll") for (int ni_ = 0; ni_ < 4; ++ni_)                         \
      acc[(AB) + mi_][ni_] = __builtin_amdgcn_mfma_f32_16x16x32_f16(          \
          ar[mi_], br[ni_], acc[(AB) + mi_][ni_], 0, 0, 0);

#define PHEAD                                                                 \
  __builtin_amdgcn_s_barrier();                                               \
  asm volatile("s_waitcnt lgkmcnt(0)" ::: "memory");                          \
  __builtin_amdgcn_sched_barrier(0);                                          \
  __builtin_amdgcn_s_setprio(1);
#define PTAIL __builtin_amdgcn_s_setprio(0); __builtin_amdgcn_s_barrier();

// MODE: 2 = stage A(next)+B(next2), vmcnt(4); 1 = stage A(next) only, vmcnt(0); 0 = none
#define KTILE(BUF, MODE)                                                      \
  DSA(a, 0, 0, BUF) DSB(b0, 0, BUF)                                           \
  if ((MODE) >= 1) { lds_load16(pA00, &sA[(BUF)^1][0][dstOff]);               \
                     lds_load16(pA01, &sA[(BUF)^1][0][4096 + dstOff]); }      \
  PHEAD MFMAQ(0, a, b0) PTAIL                                                 \
  DSA(a, 0, 1, BUF) DSB(b1, 1, BUF)                                           \
  if ((MODE) >= 1) { lds_load16(pA10, &sA[(BUF)^1][1][dstOff]);               \
                     lds_load16(pA11, &sA[(BUF)^1][1][4096 + dstOff]);        \
                     pA00 += 64; pA01 += 64; pA10 += 64; pA11 += 64; }        \
  PHEAD MFMAQ(0, a, b1) PTAIL                                                 \
  DSA(a, 1, 0, BUF)                                                           \
  if ((MODE) == 2) { lds_load16(pB00, &sB[(BUF)][0][dstOff]);                 \
                     lds_load16(pB01, &sB[(BUF)][0][4096 + dstOff]); }        \
  PHEAD MFMAQ(4, a, b0) PTAIL                                                 \
  DSA(a, 1, 1, BUF)                                                           \
  if ((MODE) == 2) { lds_load16(pB10, &sB[(BUF)][1][dstOff]);                 \
                     lds_load16(pB11, &sB[(BUF)][1][4096 + dstOff]);          \
                     pB00 += 64; pB01 += 64; pB10 += 64; pB11 += 64; }        \
  PHEAD                                                                       \
  MFMAQ(4, a, b1)                                                             \
  __builtin_amdgcn_s_setprio(0);                                              \
  if ((MODE) == 2) asm volatile("s_waitcnt vmcnt(4)" ::: "memory");           \
  if ((MODE) == 1) asm volatile("s_waitcnt vmcnt(0)" ::: "memory");           \
  __builtin_amdgcn_s_barrier();

__global__ __launch_bounds__(512, 2) void k_gemm(const _Float16* __restrict__ A,
                                                 const _Float16* __restrict__ B,
                                                 float* __restrict__ Cf,
                                                 _Float16* __restrict__ Ch,
                                                 int zf16,
                                                 unsigned* __restrict__ absmax) {
    __shared__ _Float16 sA[2][2][8192];  // [buf][half][128 rows x 64 k swizzled]
    __shared__ _Float16 sB[2][2][8192];

    // T1: bijective XCD swizzle (grid 688 = 8*86)
    int obid = blockIdx.x;
    int bid  = (obid & 7) * 86 + (obid >> 3);
    int m0 = (bid >> 4) * BM;
    int n0 = (bid & 15) * BN;

    int t = threadIdx.x, lane = t & 63, wid = t >> 6;
    int wr = wid >> 2, wc = wid & 3;
    int fr = lane & 15, g = lane >> 4;

    // staging source (inverse swizzle on global column chunk)
    int r0 = t >> 3;
    int cs = ((t & 7) ^ (r0 & 7)) * 8;
    size_t so = (size_t)r0 * IN_FEAT + cs;
    const _Float16* pA00 = A + (size_t)m0 * IN_FEAT + so;
    const _Float16* pA01 = pA00 + (size_t)64 * IN_FEAT;
    const _Float16* pA10 = pA00 + (size_t)128 * IN_FEAT;
    const _Float16* pA11 = pA00 + (size_t)192 * IN_FEAT;
    const _Float16* pB00 = B + (size_t)n0 * IN_FEAT + so;
    const _Float16* pB01 = pB00 + (size_t)64 * IN_FEAT;
    const _Float16* pB10 = pB00 + (size_t)128 * IN_FEAT;
    const _Float16* pB11 = pB00 + (size_t)192 * IN_FEAT;
    int dstOff = wid * 512;  // wave-uniform chunk base (elems)

    // fragment read bases (swizzled): phys chunk = logical ^ (fr&7)
    const _Float16* aBase = &sA[0][0][0] + wr * 8192 + fr * 64;
    const _Float16* bBase = &sB[0][0][0] + (wc >> 1) * 8192 + (wc & 1) * 4096 + fr * 64;
    int pk0 = (g ^ (fr & 7)) * 8;
    int pk1 = ((4 | g) ^ (fr & 7)) * 8;

    f32x4 acc[8][4] = {};
    f16x8 a[4], b0[4], b1[4];

    // ---- prologue: B(0), A(0) -> buf0; B(1) -> buf1
    lds_load16(pB00, &sB[0][0][dstOff]); lds_load16(pB01, &sB[0][0][4096 + dstOff]);
    lds_load16(pB10, &sB[0][1][dstOff]); lds_load16(pB11, &sB[0][1][4096 + dstOff]);
    pB00 += 64; pB01 += 64; pB10 += 64; pB11 += 64;
    lds_load16(pA00, &sA[0][0][dstOff]); lds_load16(pA01, &sA[0][0][4096 + dstOff]);
    lds_load16(pA10, &sA[0][1][dstOff]); lds_load16(pA11, &sA[0][1][4096 + dstOff]);
    pA00 += 64; pA01 += 64; pA10 += 64; pA11 += 64;
    lds_load16(pB00, &sB[1][0][dstOff]); lds_load16(pB01, &sB[1][0][4096 + dstOff]);
    lds_load16(pB10, &sB[1][1][dstOff]); lds_load16(pB11, &sB[1][1][4096 + dstOff]);
    pB00 += 64; pB01 += 64; pB10 += 64; pB11 += 64;
    asm volatile("s_waitcnt vmcnt(4)" ::: "memory");
    __builtin_amdgcn_s_barrier();

#pragma unroll 1
    for (int kt = 0; kt < NT - 2; kt += 2) {
        KTILE(0, 2)
        KTILE(1, 2)
    }
    KTILE(0, 1)
    KTILE(1, 0)

    // ---- absmax + C write (f16 path rounds first so scale matches stored Z)
    float mx = 0.f;
    if (zf16) {
#pragma unroll
        for (int mi = 0; mi < 8; ++mi) {
            int row_base = m0 + wr * 128 + mi * 16 + g * 4;
#pragma unroll
            for (int ni = 0; ni < 4; ++ni) {
                int col = n0 + wc * 64 + ni * 16 + fr;
#pragma unroll
                for (int r = 0; r < 4; ++r) {
                    _Float16 h = (_Float16)acc[mi][ni][r];
                    mx = fmaxf(mx, fabsf((float)h));
                    Ch[(size_t)(row_base + r) * IN_FEAT + col] = h;
                }
            }
        }
    } else {
#pragma unroll
        for (int mi = 0; mi < 8; ++mi) {
            int row_base = m0 + wr * 128 + mi * 16 + g * 4;
#pragma unroll
            for (int ni = 0; ni < 4; ++ni) {
                int col = n0 + wc * 64 + ni * 16 + fr;
#pragma unroll
                for (int r = 0; r < 4; ++r) {
                    float v = acc[mi][ni][r];
                    mx = fmaxf(mx, fabsf(v));
                    Cf[(size_t)(row_base + r) * IN_FEAT + col] = v;
                }
            }
        }
    }
#pragma unroll
    for (int off = 32; off; off >>= 1) mx = fmaxf(mx, __shfl_xor(mx, off));
    if (lane == 0) atomicMax(absmax, __float_as_uint(mx));
}

// ---------------------------------------------------------------- kernel 4: fake-quant
__global__ void k_quant_f16(const _Float16* __restrict__ Z, float* __restrict__ out,
                            const unsigned* __restrict__ absmax, int n8) {
    float amax  = __uint_as_float(*absmax);
    float scale = fmaxf(amax / 127.0f, 1.17549435e-38f);
    float inv   = 1.0f / scale;
    int stride = gridDim.x * blockDim.x;
    for (int i = blockIdx.x * blockDim.x + threadIdx.x; i < n8; i += stride) {
        f16x8 v = *(const f16x8*)&Z[(size_t)i * 8];
        float4 o1, o2;
        o1.x = fminf(127.f, fmaxf(-127.f, rintf((float)v[0] * inv))) * scale;
        o1.y = fminf(127.f, fmaxf(-127.f, rintf((float)v[1] * inv))) * scale;
        o1.z = fminf(127.f, fmaxf(-127.f, rintf((float)v[2] * inv))) * scale;
        o1.w = fminf(127.f, fmaxf(-127.f, rintf((float)v[3] * inv))) * scale;
        o2.x = fminf(127.f, fmaxf(-127.f, rintf((float)v[4] * inv))) * scale;
        o2.y = fminf(127.f, fmaxf(-127.f, rintf((float)v[5] * inv))) * scale;
        o2.z = fminf(127.f, fmaxf(-127.f, rintf((float)v[6] * inv))) * scale;
        o2.w = fminf(127.f, fmaxf(-127.f, rintf((float)v[7] * inv))) * scale;
        ((float4*)out)[i * 2]     = o1;
        ((float4*)out)[i * 2 + 1] = o2;
    }
}

__global__ void k_quant_f32(float* __restrict__ C, const unsigned* __restrict__ absmax, int n4) {
    float amax  = __uint_as_float(*absmax);
    float scale = fmaxf(amax / 127.0f, 1.17549435e-38f);
    float inv   = 1.0f / scale;
    int stride = gridDim.x * blockDim.x;
    for (int i = blockIdx.x * blockDim.x + threadIdx.x; i < n4; i += stride) {
        float4 v = ((const float4*)C)[i];
        float4 o;
        o.x = fminf(127.f, fmaxf(-127.f, rintf(v.x * inv))) * scale;
        o.y = fminf(127.f, fmaxf(-127.f, rintf(v.y * inv))) * scale;
        o.z = fminf(127.f, fmaxf(-127.f, rintf(v.z * inv))) * scale;
        o.w = fminf(127.f, fmaxf(-127.f, rintf(v.w * inv))) * scale;
        ((float4*)C)[i] = o;
    }
}

// ---------------------------------------------------------------- launch
extern "C" void kernel_launch(void* const* d_in, const int* in_sizes, int n_in,
                              void* d_out, int out_size, void* d_ws, size_t ws_size,
                              hipStream_t stream) {
    const float* inp = (const float*)d_in[0];
    const float* Rl  = (const float*)d_in[1];
    const float* Rr  = (const float*)d_in[2];
    float* out = (float*)d_out;

    char* ws = (char*)d_ws;
    const size_t W_BYTES  = (size_t)OUT_FEAT * IN_FEAT * 2;  // 90,177,536
    const size_t BT_BYTES = (size_t)IN_FEAT * IN_FEAT * 2;   // 33,554,432
    _Float16* Wh   = (_Float16*)ws;
    _Float16* Bt   = (_Float16*)(ws + W_BYTES);
    unsigned* amax = (unsigned*)(ws + W_BYTES + BT_BYTES);
    _Float16* Zh   = (_Float16*)(ws + W_BYTES + BT_BYTES + 1024);
    size_t needed  = W_BYTES + BT_BYTES + 1024 + W_BYTES;  // Zh is f16, same size as Wh
    int zf16 = (ws_size >= needed) ? 1 : 0;

    // merged prep: 4096 transpose + 2752 rotate blocks, Bresenham-interleaved (also zeroes amax)
    k_prep<<<dim3(4096 + 2752), 256, 0, stream>>>(Rl, Rr, inp, Bt, (__half*)Wh, amax);
    k_gemm<<<dim3((OUT_FEAT / BM) * (IN_FEAT / BN)), 512, 0, stream>>>(Wh, Bt, out, Zh, zf16, amax);
    if (zf16) {
        int n8 = OUT_FEAT * IN_FEAT / 8;
        k_quant_f16<<<2048, 256, 0, stream>>>(Zh, out, amax, n8);
    } else {
        int n4 = OUT_FEAT * IN_FEAT / 4;
        k_quant_f32<<<2048, 256, 0, stream>>>(out, amax, n4);
    }
}

// Round 12
// 582.092 us; speedup vs baseline: 1.0479x; 1.0479x over previous
//
#include <hip/hip_runtime.h>
#include <hip/hip_fp16.h>

#define OUT_FEAT 11008
#define IN_FEAT  4096
#define HAD      128

typedef __attribute__((ext_vector_type(8))) _Float16 f16x8;
typedef __attribute__((ext_vector_type(4))) float    f32x4;

// ---------------------------------------------------------------- stage 16B/lane
__device__ __forceinline__ void lds_load16(const _Float16* g, _Float16* l) {
    __builtin_amdgcn_global_load_lds(
        (const __attribute__((address_space(1))) void*)g,
        (__attribute__((address_space(3))) void*)l, 16, 0, 0);
}

// ---------------------------------------------------------------- kernel 1: merged prep (R10 contiguous layout — measured best)
// blocks [0, 4096):   Bt[n][k] = (f16)R_left[k][n]   (transpose+convert, 64x64 tiles)
// blocks [4096, 6848): W[b*128+j, i] = sum_k Rr[k,j]*inp[b*128+k, i]  (packed-f16 rotate)
// block 0 lane 0 additionally zeroes amax (prep precedes gemm's atomics on the stream).
__global__ __launch_bounds__(256, 2) void k_prep(const float* __restrict__ Rl,
                                                 const float* __restrict__ Rr,
                                                 const float* __restrict__ inp,
                                                 _Float16* __restrict__ Bt,
                                                 __half* __restrict__ W,
                                                 unsigned* __restrict__ amax) {
    __shared__ char smem[65536];
    int bid = blockIdx.x;
    int t   = threadIdx.x;

    if (bid < 4096) {
        if (bid == 0 && t == 0) *amax = 0u;
        // ---------------- transpose+convert ----------------
        float (*tile)[65] = (float(*)[65])smem;
        int n0 = (bid & 63) * 64;
        int k0 = (bid >> 6) * 64;
        int tn = t & 63;
        int tr = t >> 6;
#pragma unroll
        for (int r = 0; r < 16; ++r) {
            int kk = r * 4 + tr;
            tile[kk][tn] = Rl[(size_t)(k0 + kk) * IN_FEAT + n0 + tn];
        }
        __syncthreads();
#pragma unroll
        for (int r = 0; r < 16; ++r) {
            int nn = r * 4 + tr;
            Bt[(size_t)(n0 + nn) * IN_FEAT + k0 + tn] = (_Float16)tile[tn][nn];
        }
        return;
    }

    // ---------------- rotate (packed f16, contiguous b128 LDS reads) ----------------
    __half2* sR2 = (__half2*)smem;            // [k][64 j-pairs]  32 KB
    __half2* sX2 = (__half2*)(smem + 32768);  // [k][64 i-pairs]  32 KB
    int rb = bid - 4096;
    int i0 = (rb & 31) * 128;
    int b  = rb >> 5;

#pragma unroll
    for (int r = 0; r < 32; ++r) {
        int idx = r * 256 + t;  // half2 index
        float2 v = *(const float2*)&Rr[(size_t)idx * 2];
        sR2[idx] = __floats2half2_rn(v.x, v.y);
    }
    const float* xsrc = inp + (size_t)b * HAD * IN_FEAT + i0;
#pragma unroll
    for (int r = 0; r < 32; ++r) {
        int idx = r * 256 + t;
        int k = idx >> 6, ip = idx & 63;
        float2 v = *(const float2*)&xsrc[(size_t)k * IN_FEAT + ip * 2];
        sX2[idx] = __floats2half2_rn(v.x, v.y);
    }
    __syncthreads();

    int tx = t & 15, ty = t >> 4;
    __half2 acc2[8][4];
#pragma unroll
    for (int j = 0; j < 8; ++j)
#pragma unroll
        for (int c = 0; c < 4; ++c) acc2[j][c] = __float2half2_rn(0.f);

    for (int k = 0; k < 128; ++k) {
        const __half2* rp = &sR2[k * 64 + ty * 4];
        __half2 rr[4] = {rp[0], rp[1], rp[2], rp[3]};
        const __half2* xp = &sX2[k * 64 + tx * 4];
        __half2 xv[4] = {xp[0], xp[1], xp[2], xp[3]};
#pragma unroll
        for (int q = 0; q < 4; ++q) {
            __half2 rlo = __low2half2(rr[q]);
            __half2 rhi = __high2half2(rr[q]);
#pragma unroll
            for (int c = 0; c < 4; ++c) {
                acc2[2 * q][c]     = __hfma2(rlo, xv[c], acc2[2 * q][c]);
                acc2[2 * q + 1][c] = __hfma2(rhi, xv[c], acc2[2 * q + 1][c]);
            }
        }
    }

#pragma unroll
    for (int jj = 0; jj < 8; ++jj) {
        size_t row = (size_t)(b * HAD + ty * 8 + jj) * IN_FEAT;
        union { __half2 h2[4]; f16x8 v; } u;
#pragma unroll
        for (int c = 0; c < 4; ++c) u.h2[c] = acc2[jj][c];
        *(f16x8*)&W[row + i0 + tx * 8] = u.v;
    }
}

// ---------------------------------------------------------------- kernel 3: 256x256 BK=64, branch-free unrolled pipeline
// Measured-best structure (R8/R10: ~440-449 us, MfmaUtil 36.5%, 0 bank conflicts). FROZEN.
#define BM 256
#define BN 256
#define BK 64
#define NT 64  // IN_FEAT / BK

#define DSA(dst, MH, KS, BUF)                                                 \
  _Pragma("unroll") for (int i_ = 0; i_ < 4; ++i_)                            \
      dst[i_] = *(const f16x8*)(aBase + (BUF)*16384 + ((MH)*4 + i_)*1024 +    \
                                ((KS) ? pk1 : pk0));

#define DSB(dst, KS, BUF)                                                     \
  _Pragma("unroll") for (int i_ = 0; i_ < 4; ++i_)                            \
      dst[i_] = *(const f16x8*)(bBase + (BUF)*16384 + i_*1024 +               \
                                ((KS) ? pk1 : pk0));

#define MFMAQ(AB, ar, br)                                                     \
  _Pragma("unroll") for (int mi_ = 0; mi_ < 4; ++mi_)                         \
  _Pragma("unroll") for (int ni_ = 0; ni_ < 4; ++ni_)                         \
      acc[(AB) + mi_][ni_] = __builtin_amdgcn_mfma_f32_16x16x32_f16(          \
          ar[mi_], br[ni_], acc[(AB) + mi_][ni_], 0, 0, 0);

#define PHEAD                                                                 \
  __builtin_amdgcn_s_barrier();                                               \
  asm volatile("s_waitcnt lgkmcnt(0)" ::: "memory");                          \
  __builtin_amdgcn_sched_barrier(0);                                          \
  __builtin_amdgcn_s_setprio(1);
#define PTAIL __builtin_amdgcn_s_setprio(0); __builtin_amdgcn_s_barrier();

// MODE: 2 = stage A(next)+B(next2), vmcnt(4); 1 = stage A(next) only, vmcnt(0); 0 = none
#define KTILE(BUF, MODE)                                                      \
  DSA(a, 0, 0, BUF) DSB(b0, 0, BUF)                                           \
  if ((MODE) >= 1) { lds_load16(pA00, &sA[(BUF)^1][0][dstOff]);               \
                     lds_load16(pA01, &sA[(BUF)^1][0][4096 + dstOff]); }      \
  PHEAD MFMAQ(0, a, b0) PTAIL                                                 \
  DSA(a, 0, 1, BUF) DSB(b1, 1, BUF)                                           \
  if ((MODE) >= 1) { lds_load16(pA10, &sA[(BUF)^1][1][dstOff]);               \
                     lds_load16(pA11, &sA[(BUF)^1][1][4096 + dstOff]);        \
                     pA00 += 64; pA01 += 64; pA10 += 64; pA11 += 64; }        \
  PHEAD MFMAQ(0, a, b1) PTAIL                                                 \
  DSA(a, 1, 0, BUF)                                                           \
  if ((MODE) == 2) { lds_load16(pB00, &sB[(BUF)][0][dstOff]);                 \
                     lds_load16(pB01, &sB[(BUF)][0][4096 + dstOff]); }        \
  PHEAD MFMAQ(4, a, b0) PTAIL                                                 \
  DSA(a, 1, 1, BUF)                                                           \
  if ((MODE) == 2) { lds_load16(pB10, &sB[(BUF)][1][dstOff]);                 \
                     lds_load16(pB11, &sB[(BUF)][1][4096 + dstOff]);          \
                     pB00 += 64; pB01 += 64; pB10 += 64; pB11 += 64; }        \
  PHEAD                                                                       \
  MFMAQ(4, a, b1)                                                             \
  __builtin_amdgcn_s_setprio(0);                                              \
  if ((MODE) == 2) asm volatile("s_waitcnt vmcnt(4)" ::: "memory");           \
  if ((MODE) == 1) asm volatile("s_waitcnt vmcnt(0)" ::: "memory");           \
  __builtin_amdgcn_s_barrier();

__global__ __launch_bounds__(512, 2) void k_gemm(const _Float16* __restrict__ A,
                                                 const _Float16* __restrict__ B,
                                                 float* __restrict__ Cf,
                                                 _Float16* __restrict__ Ch,
                                                 int zf16,
                                                 unsigned* __restrict__ absmax) {
    __shared__ _Float16 sA[2][2][8192];  // [buf][half][128 rows x 64 k swizzled]
    __shared__ _Float16 sB[2][2][8192];

    // T1: bijective XCD swizzle (grid 688 = 8*86)
    int obid = blockIdx.x;
    int bid  = (obid & 7) * 86 + (obid >> 3);
    int m0 = (bid >> 4) * BM;
    int n0 = (bid & 15) * BN;

    int t = threadIdx.x, lane = t & 63, wid = t >> 6;
    int wr = wid >> 2, wc = wid & 3;
    int fr = lane & 15, g = lane >> 4;

    // staging source (inverse swizzle on global column chunk)
    int r0 = t >> 3;
    int cs = ((t & 7) ^ (r0 & 7)) * 8;
    size_t so = (size_t)r0 * IN_FEAT + cs;
    const _Float16* pA00 = A + (size_t)m0 * IN_FEAT + so;
    const _Float16* pA01 = pA00 + (size_t)64 * IN_FEAT;
    const _Float16* pA10 = pA00 + (size_t)128 * IN_FEAT;
    const _Float16* pA11 = pA00 + (size_t)192 * IN_FEAT;
    const _Float16* pB00 = B + (size_t)n0 * IN_FEAT + so;
    const _Float16* pB01 = pB00 + (size_t)64 * IN_FEAT;
    const _Float16* pB10 = pB00 + (size_t)128 * IN_FEAT;
    const _Float16* pB11 = pB00 + (size_t)192 * IN_FEAT;
    int dstOff = wid * 512;  // wave-uniform chunk base (elems)

    // fragment read bases (swizzled): phys chunk = logical ^ (fr&7)
    const _Float16* aBase = &sA[0][0][0] + wr * 8192 + fr * 64;
    const _Float16* bBase = &sB[0][0][0] + (wc >> 1) * 8192 + (wc & 1) * 4096 + fr * 64;
    int pk0 = (g ^ (fr & 7)) * 8;
    int pk1 = ((4 | g) ^ (fr & 7)) * 8;

    f32x4 acc[8][4] = {};
    f16x8 a[4], b0[4], b1[4];

    // ---- prologue: B(0), A(0) -> buf0; B(1) -> buf1
    lds_load16(pB00, &sB[0][0][dstOff]); lds_load16(pB01, &sB[0][0][4096 + dstOff]);
    lds_load16(pB10, &sB[0][1][dstOff]); lds_load16(pB11, &sB[0][1][4096 + dstOff]);
    pB00 += 64; pB01 += 64; pB10 += 64; pB11 += 64;
    lds_load16(pA00, &sA[0][0][dstOff]); lds_load16(pA01, &sA[0][0][4096 + dstOff]);
    lds_load16(pA10, &sA[0][1][dstOff]); lds_load16(pA11, &sA[0][1][4096 + dstOff]);
    pA00 += 64; pA01 += 64; pA10 += 64; pA11 += 64;
    lds_load16(pB00, &sB[1][0][dstOff]); lds_load16(pB01, &sB[1][0][4096 + dstOff]);
    lds_load16(pB10, &sB[1][1][dstOff]); lds_load16(pB11, &sB[1][1][4096 + dstOff]);
    pB00 += 64; pB01 += 64; pB10 += 64; pB11 += 64;
    asm volatile("s_waitcnt vmcnt(4)" ::: "memory");
    __builtin_amdgcn_s_barrier();

#pragma unroll 1
    for (int kt = 0; kt < NT - 2; kt += 2) {
        KTILE(0, 2)
        KTILE(1, 2)
    }
    KTILE(0, 1)
    KTILE(1, 0)

    // ---- absmax + C write (f16 path rounds first so scale matches stored Z)
    float mx = 0.f;
    if (zf16) {
#pragma unroll
        for (int mi = 0; mi < 8; ++mi) {
            int row_base = m0 + wr * 128 + mi * 16 + g * 4;
#pragma unroll
            for (int ni = 0; ni < 4; ++ni) {
                int col = n0 + wc * 64 + ni * 16 + fr;
#pragma unroll
                for (int r = 0; r < 4; ++r) {
                    _Float16 h = (_Float16)acc[mi][ni][r];
                    mx = fmaxf(mx, fabsf((float)h));
                    Ch[(size_t)(row_base + r) * IN_FEAT + col] = h;
                }
            }
        }
    } else {
#pragma unroll
        for (int mi = 0; mi < 8; ++mi) {
            int row_base = m0 + wr * 128 + mi * 16 + g * 4;
#pragma unroll
            for (int ni = 0; ni < 4; ++ni) {
                int col = n0 + wc * 64 + ni * 16 + fr;
#pragma unroll
                for (int r = 0; r < 4; ++r) {
                    float v = acc[mi][ni][r];
                    mx = fmaxf(mx, fabsf(v));
                    Cf[(size_t)(row_base + r) * IN_FEAT + col] = v;
                }
            }
        }
    }
#pragma unroll
    for (int off = 32; off; off >>= 1) mx = fmaxf(mx, __shfl_xor(mx, off));
    if (lane == 0) atomicMax(absmax, __float_as_uint(mx));
}

// ---------------------------------------------------------------- kernel 4: fake-quant
__global__ void k_quant_f16(const _Float16* __restrict__ Z, float* __restrict__ out,
                            const unsigned* __restrict__ absmax, int n8) {
    float amax  = __uint_as_float(*absmax);
    float scale = fmaxf(amax / 127.0f, 1.17549435e-38f);
    float inv   = 1.0f / scale;
    int stride = gridDim.x * blockDim.x;
    for (int i = blockIdx.x * blockDim.x + threadIdx.x; i < n8; i += stride) {
        f16x8 v = *(const f16x8*)&Z[(size_t)i * 8];
        float4 o1, o2;
        o1.x = fminf(127.f, fmaxf(-127.f, rintf((float)v[0] * inv))) * scale;
        o1.y = fminf(127.f, fmaxf(-127.f, rintf((float)v[1] * inv))) * scale;
        o1.z = fminf(127.f, fmaxf(-127.f, rintf((float)v[2] * inv))) * scale;
        o1.w = fminf(127.f, fmaxf(-127.f, rintf((float)v[3] * inv))) * scale;
        o2.x = fminf(127.f, fmaxf(-127.f, rintf((float)v[4] * inv))) * scale;
        o2.y = fminf(127.f, fmaxf(-127.f, rintf((float)v[5] * inv))) * scale;
        o2.z = fminf(127.f, fmaxf(-127.f, rintf((float)v[6] * inv))) * scale;
        o2.w = fminf(127.f, fmaxf(-127.f, rintf((float)v[7] * inv))) * scale;
        ((float4*)out)[i * 2]     = o1;
        ((float4*)out)[i * 2 + 1] = o2;
    }
}

__global__ void k_quant_f32(float* __restrict__ C, const unsigned* __restrict__ absmax, int n4) {
    float amax  = __uint_as_float(*absmax);
    float scale = fmaxf(amax / 127.0f, 1.17549435e-38f);
    float inv   = 1.0f / scale;
    int stride = gridDim.x * blockDim.x;
    for (int i = blockIdx.x * blockDim.x + threadIdx.x; i < n4; i += stride) {
        float4 v = ((const float4*)C)[i];
        float4 o;
        o.x = fminf(127.f, fmaxf(-127.f, rintf(v.x * inv))) * scale;
        o.y = fminf(127.f, fmaxf(-127.f, rintf(v.y * inv))) * scale;
        o.z = fminf(127.f, fmaxf(-127.f, rintf(v.z * inv))) * scale;
        o.w = fminf(127.f, fmaxf(-127.f, rintf(v.w * inv))) * scale;
        ((float4*)C)[i] = o;
    }
}

// ---------------------------------------------------------------- launch
extern "C" void kernel_launch(void* const* d_in, const int* in_sizes, int n_in,
                              void* d_out, int out_size, void* d_ws, size_t ws_size,
                              hipStream_t stream) {
    const float* inp = (const float*)d_in[0];
    const float* Rl  = (const float*)d_in[1];
    const float* Rr  = (const float*)d_in[2];
    float* out = (float*)d_out;

    char* ws = (char*)d_ws;
    const size_t W_BYTES  = (size_t)OUT_FEAT * IN_FEAT * 2;  // 90,177,536
    const size_t BT_BYTES = (size_t)IN_FEAT * IN_FEAT * 2;   // 33,554,432
    _Float16* Wh   = (_Float16*)ws;
    _Float16* Bt   = (_Float16*)(ws + W_BYTES);
    unsigned* amax = (unsigned*)(ws + W_BYTES + BT_BYTES);
    _Float16* Zh   = (_Float16*)(ws + W_BYTES + BT_BYTES + 1024);
    size_t needed  = W_BYTES + BT_BYTES + 1024 + W_BYTES;  // Zh is f16, same size as Wh
    int zf16 = (ws_size >= needed) ? 1 : 0;

    // merged prep: 4096 transpose blocks + 2752 rotate blocks (also zeroes amax)
    k_prep<<<dim3(4096 + 2752), 256, 0, stream>>>(Rl, Rr, inp, Bt, (__half*)Wh, amax);
    k_gemm<<<dim3((OUT_FEAT / BM) * (IN_FEAT / BN)), 512, 0, stream>>>(Wh, Bt, out, Zh, zf16, amax);
    if (zf16) {
        int n8 = OUT_FEAT * IN_FEAT / 8;
        k_quant_f16<<<2048, 256, 0, stream>>>(Zh, out, amax, n8);
    } else {
        int n4 = OUT_FEAT * IN_FEAT / 4;
        k_quant_f32<<<2048, 256, 0, stream>>>(out, amax, n4);
    }
}